// Round 1
// baseline (282.203 us; speedup 1.0000x reference)
//
#include <hip/hip_runtime.h>
#include <hip/hip_bf16.h>
#include <stdint.h>

#define N_LGN   17400
#define N_POST  50000
#define NNZ     800000
#define N_BASIS 5
#define ELL_CAP 48

#define TPOSE_CBLK   32
#define TPOSE_BLOCKS ((N_LGN + TPOSE_CBLK - 1) / TPOSE_CBLK)   // 544
#define SCAT_THREADS (NNZ / 4)                                  // 200000 (4 edges/thread)
#define SCAT_BLOCKS  ((SCAT_THREADS + 255) / 256)               // 782

// ---------------- fused prep: scatter (blocks [0,782)) + transpose (blocks [782,1326)) ----
// The two phases are independent (different inputs, different outputs) and stress different
// resources (atomic latency vs. VMEM latency) — overlapping them hides both.
__global__ __launch_bounds__(256) void k_prep(const float* __restrict__ inp,
                                              __hip_bfloat162* __restrict__ xTb,
                                              const int4* __restrict__ idx4,
                                              const float4* __restrict__ w4,
                                              const int4* __restrict__ syn4,
                                              int* __restrict__ counts,
                                              int2* __restrict__ ell) {
    __shared__ float tile[TPOSE_CBLK * 129];   // [c_local][s], pitch 129 breaks bank conflicts
    int tid = threadIdx.x;
    if (blockIdx.x < SCAT_BLOCKS) {
        // ---- ELL scatter, 4 edges per thread = 4 independent atomic chains ----
        int t = blockIdx.x * 256 + tid;
        if (t >= SCAT_THREADS) return;
        int4 iA = idx4[2 * t];          // edges 4t,4t+1: (row,col,row,col)
        int4 iB = idx4[2 * t + 1];      // edges 4t+2,4t+3
        float4 ww = w4[t];
        int4 sy = syn4[t];
        int r0 = atomicAdd(&counts[iA.x], 1);
        if (r0 < ELL_CAP) ell[iA.x * ELL_CAP + r0] = make_int2(iA.y | (sy.x << 16), __float_as_int(ww.x));
        int r1 = atomicAdd(&counts[iA.z], 1);
        if (r1 < ELL_CAP) ell[iA.z * ELL_CAP + r1] = make_int2(iA.w | (sy.y << 16), __float_as_int(ww.y));
        int r2 = atomicAdd(&counts[iB.x], 1);
        if (r2 < ELL_CAP) ell[iB.x * ELL_CAP + r2] = make_int2(iB.y | (sy.z << 16), __float_as_int(ww.z));
        int r3 = atomicAdd(&counts[iB.z], 1);
        if (r3 < ELL_CAP) ell[iB.z * ELL_CAP + r3] = make_int2(iB.w | (sy.w << 16), __float_as_int(ww.w));
    } else {
        // ---- transpose x (128 x 17400) fp32 -> xTb (17400 x 64) bf16x2, 32-col tiles ----
        int c0 = (blockIdx.x - SCAT_BLOCKS) * TPOSE_CBLK;
        for (int it = 0; it < 16; ++it) {
            int flat = it * 256 + tid;          // 0..4095 = 128 s x 32 c
            int s  = flat >> 5;
            int cl = flat & 31;
            int c  = c0 + cl;
            float v = 0.0f;
            if (c < N_LGN) v = inp[s * N_LGN + c];
            tile[cl * 129 + s] = v;
        }
        __syncthreads();
        for (int it = 0; it < 8; ++it) {
            int flat = it * 256 + tid;          // 0..2047 = 32 c x 64 sp
            int cl = flat >> 6;
            int sp = flat & 63;
            int c  = c0 + cl;
            if (c < N_LGN) {
                float2 f = make_float2(tile[cl * 129 + 2 * sp], tile[cl * 129 + 2 * sp + 1]);
                xTb[c * 64 + sp] = __float22bfloat162_rn(f);
            }
        }
    }
}

// ---------------- CSR fallback path (used only if ws too small for ELL) ----------------
__global__ __launch_bounds__(256) void k_transpose_bf16(const float* __restrict__ inp,
                                                        __hip_bfloat162* __restrict__ xTb) {
    __shared__ float tile[64 * 129];
    int c0  = blockIdx.x * 64;
    int tid = threadIdx.x;
    for (int it = 0; it < 32; ++it) {
        int flat = it * 256 + tid;
        int s  = flat >> 6;
        int cl = flat & 63;
        int c  = c0 + cl;
        float v = 0.0f;
        if (c < N_LGN) v = inp[s * N_LGN + c];
        tile[cl * 129 + s] = v;
    }
    __syncthreads();
    for (int it = 0; it < 16; ++it) {
        int flat = it * 256 + tid;
        int cl = flat >> 6;
        int sp = flat & 63;
        int c  = c0 + cl;
        if (c < N_LGN) {
            float2 f = make_float2(tile[cl * 129 + 2 * sp], tile[cl * 129 + 2 * sp + 1]);
            xTb[c * 64 + sp] = __float22bfloat162_rn(f);
        }
    }
}

__global__ __launch_bounds__(256) void k_hist(const int4* __restrict__ idx2,
                                              int* __restrict__ counts) {
    int t = blockIdx.x * 256 + threadIdx.x;
    if (t >= NNZ / 2) return;
    int4 rc = idx2[t];
    atomicAdd(&counts[rc.x], 1);
    atomicAdd(&counts[rc.z], 1);
}

__global__ __launch_bounds__(1024) void k_scan1(const int* __restrict__ counts,
                                                int* __restrict__ rowStart,
                                                int* __restrict__ blockSums) {
    __shared__ int tmp[1024];
    int tid = threadIdx.x;
    int gid = blockIdx.x * 1024 + tid;
    int v = (gid < N_POST) ? counts[gid] : 0;
    tmp[tid] = v;
    __syncthreads();
    for (int off = 1; off < 1024; off <<= 1) {
        int t = (tid >= off) ? tmp[tid - off] : 0;
        __syncthreads();
        tmp[tid] += t;
        __syncthreads();
    }
    if (gid < N_POST) rowStart[gid] = tmp[tid] - v;
    if (tid == 1023) blockSums[blockIdx.x] = tmp[1023];
}

__global__ __launch_bounds__(64) void k_scan2(const int* __restrict__ blockSums,
                                              int* __restrict__ blockOffsets, int nblk) {
    __shared__ int tmp[64];
    int tid = threadIdx.x;
    int v = (tid < nblk) ? blockSums[tid] : 0;
    tmp[tid] = v;
    __syncthreads();
    for (int off = 1; off < 64; off <<= 1) {
        int t = (tid >= off) ? tmp[tid - off] : 0;
        __syncthreads();
        tmp[tid] += t;
        __syncthreads();
    }
    if (tid < nblk) blockOffsets[tid] = tmp[tid] - v;
}

__global__ __launch_bounds__(1024) void k_scan3(int* __restrict__ rowStart,
                                                const int* __restrict__ blockOffsets) {
    int gid = blockIdx.x * 1024 + threadIdx.x;
    if (gid < N_POST) rowStart[gid] += blockOffsets[blockIdx.x];
}

__global__ __launch_bounds__(256) void k_scatter_csr(const int4* __restrict__ idx2,
                                                     const float2* __restrict__ w2,
                                                     const int2* __restrict__ syn2,
                                                     const int* __restrict__ rowStart,
                                                     int* __restrict__ cursor,
                                                     int2* __restrict__ edges) {
    int t = blockIdx.x * 256 + threadIdx.x;
    if (t >= NNZ / 2) return;
    int4 rc = idx2[t];
    float2 ww = w2[t];
    int2 sy = syn2[t];
    int p0 = rowStart[rc.x] + atomicAdd(&cursor[rc.x], 1);
    edges[p0] = make_int2(rc.y | (sy.x << 16), __float_as_int(ww.x));
    int p1 = rowStart[rc.z] + atomicAdd(&cursor[rc.z], 1);
    edges[p1] = make_int2(rc.w | (sy.y << 16), __float_as_int(ww.y));
}

// ---------------- main compute: one wave per row, 4-edge unroll + quad prefetch ----------
__global__ __launch_bounds__(512, 8) void k_compute(const __hip_bfloat162* __restrict__ xTb,
                                                    const int2* __restrict__ edges,
                                                    const int* __restrict__ rowStart,
                                                    const int* __restrict__ counts,
                                                    const float* __restrict__ sw,
                                                    float2* __restrict__ out2,
                                                    int cap, int useEll) {
    __shared__ float facs[64];              // synaptic_weights: 10x5 = 50 floats
    __shared__ float accLds[40 * 133];      // [j = wave*5+r][s], pitch 133: bank step 10 -> 16 banks
    int tid  = threadIdx.x;
    if (tid < 50) facs[tid] = sw[tid];
    int wave = tid >> 6;
    int lane = tid & 63;
    int n     = blockIdx.x * 8 + wave;      // 6250*8 == 50000 exactly
    int start = useEll ? n * cap : rowStart[n];
    int cnt   = counts[n];
    if (cnt > cap) cnt = cap;
    __syncthreads();

    float a0[N_BASIS] = {0.f, 0.f, 0.f, 0.f, 0.f};
    float a1[N_BASIS] = {0.f, 0.f, 0.f, 0.f, 0.f};

    const int2* ep = edges + start;
    int j = 0;
    if ((((uintptr_t)ep) & 15) == 0 && cnt >= 4) {   // ELL rows are 16B aligned (48*8B)
        const int4* ep4 = (const int4*)ep;           // 2 edges per int4
        int nq = cnt >> 2;
        j = nq << 2;
        int4 E0 = ep4[0];
        int4 E1 = ep4[1];
        for (int q = 0; q < nq; ++q) {
            // prefetch next quad's descriptors (clamped re-read on last iter: never OOB)
            int pi = (q + 1 < nq) ? (2 * q + 2) : (2 * q);
            int4 N0 = ep4[pi];
            int4 N1 = ep4[pi + 1];
            int c0 = E0.x & 0xFFFF, sy0 = E0.x >> 16;
            int c1 = E0.z & 0xFFFF, sy1 = E0.z >> 16;
            int c2 = E1.x & 0xFFFF, sy2 = E1.x >> 16;
            int c3 = E1.z & 0xFFFF, sy3 = E1.z >> 16;
            float2 x0 = __bfloat1622float2(xTb[c0 * 64 + lane]);   // 4 gathers in flight
            float2 x1 = __bfloat1622float2(xTb[c1 * 64 + lane]);
            float2 x2 = __bfloat1622float2(xTb[c2 * 64 + lane]);
            float2 x3 = __bfloat1622float2(xTb[c3 * 64 + lane]);
            float w0 = __int_as_float(E0.y);
            float w1 = __int_as_float(E0.w);
            float w2 = __int_as_float(E1.y);
            float w3 = __int_as_float(E1.w);
#pragma unroll
            for (int r = 0; r < N_BASIS; ++r) {
                float f0 = w0 * facs[sy0 * 5 + r];   // wave-uniform LDS reads: broadcast
                float f1 = w1 * facs[sy1 * 5 + r];
                float f2 = w2 * facs[sy2 * 5 + r];
                float f3 = w3 * facs[sy3 * 5 + r];
                a0[r] = fmaf(x0.x, f0, a0[r]);  a1[r] = fmaf(x0.y, f0, a1[r]);
                a0[r] = fmaf(x1.x, f1, a0[r]);  a1[r] = fmaf(x1.y, f1, a1[r]);
                a0[r] = fmaf(x2.x, f2, a0[r]);  a1[r] = fmaf(x2.y, f2, a1[r]);
                a0[r] = fmaf(x3.x, f3, a0[r]);  a1[r] = fmaf(x3.y, f3, a1[r]);
            }
            E0 = N0; E1 = N1;
        }
    }
    for (; j < cnt; ++j) {
        int2 e0 = ep[j];
        int c0 = e0.x & 0xFFFF, sy0 = e0.x >> 16;
        float2 x0 = __bfloat1622float2(xTb[c0 * 64 + lane]);
        float w0 = __int_as_float(e0.y);
#pragma unroll
        for (int r = 0; r < N_BASIS; ++r) {
            float f0 = w0 * facs[sy0 * 5 + r];
            a0[r] = fmaf(x0.x, f0, a0[r]);
            a1[r] = fmaf(x0.y, f0, a1[r]);
        }
    }

#pragma unroll
    for (int r = 0; r < N_BASIS; ++r) {
        int jj = wave * 5 + r;
        accLds[jj * 133 + 2 * lane]     = a0[r];   // s = 2*lane
        accLds[jj * 133 + 2 * lane + 1] = a1[r];   // s = 2*lane+1
    }
    __syncthreads();

    // epilogue: 128 s x 40 floats = 2560 float2; contiguous 160B runs per s
    int base2 = blockIdx.x * 20;
    for (int it = 0; it < 5; ++it) {
        int flat = it * 512 + tid;          // 0..2559
        int s  = flat / 20;
        int jj = flat % 20;
        float f0 = accLds[(2 * jj) * 133 + s];
        float f1 = accLds[(2 * jj + 1) * 133 + s];
        out2[s * 125000 + base2 + jj] = make_float2(f0, f1);
    }
}

// ---------------- launcher ----------------
extern "C" void kernel_launch(void* const* d_in, const int* in_sizes, int n_in,
                              void* d_out, int out_size, void* d_ws, size_t ws_size,
                              hipStream_t stream) {
    const float* inp     = (const float*)d_in[0];   // (1,128,17400) fp32
    const int*   indices = (const int*)d_in[1];     // (800000,2)
    const float* weights = (const float*)d_in[2];   // (800000,)
    const float* sw      = (const float*)d_in[3];   // (10,5)
    const int*   syn     = (const int*)d_in[4];     // (800000,)

    char* ws = (char*)d_ws;
    __hip_bfloat162* xTb = (__hip_bfloat162*)(ws);          // 17400*64*4 = 4,454,400 B
    int* counts          = (int*)(ws + 4454400);            // 200,000 B

    const size_t ELL_BYTES_END = 4654400ULL + (size_t)N_POST * ELL_CAP * 8;  // 23,854,400
    bool useEll = (ws_size >= ELL_BYTES_END);

    if (useEll) {
        int2* ell = (int2*)(ws + 4654400);                  // 19,200,000 B
        hipMemsetAsync(counts, 0, 200000, stream);
        k_prep<<<SCAT_BLOCKS + TPOSE_BLOCKS, 256, 0, stream>>>(
            inp, xTb, (const int4*)indices, (const float4*)weights, (const int4*)syn,
            counts, ell);
        k_compute<<<N_POST / 8, 512, 0, stream>>>(xTb, ell, nullptr, counts, sw,
                                                  (float2*)d_out, ELL_CAP, 1);
    } else {
        int* cursor    = (int*)(ws + 4654400);              // 200,000 B (adjacent to counts)
        int* rowStart  = (int*)(ws + 4854400);              // 200,000 B
        int* blockSums = (int*)(ws + 5054400);              // 256 B
        int* blockOffs = (int*)(ws + 5054656);              // 256 B
        int2* edges    = (int2*)(ws + 5054912);             // 6,400,000 B
        hipMemsetAsync(counts, 0, 400000, stream);          // counts + cursor
        k_transpose_bf16<<<(N_LGN + 63) / 64, 256, 0, stream>>>(inp, xTb);
        k_hist<<<(NNZ / 2 + 255) / 256, 256, 0, stream>>>((const int4*)indices, counts);
        k_scan1<<<(N_POST + 1023) / 1024, 1024, 0, stream>>>(counts, rowStart, blockSums);
        k_scan2<<<1, 64, 0, stream>>>(blockSums, blockOffs, (N_POST + 1023) / 1024);
        k_scan3<<<(N_POST + 1023) / 1024, 1024, 0, stream>>>(rowStart, blockOffs);
        k_scatter_csr<<<(NNZ / 2 + 255) / 256, 256, 0, stream>>>(
            (const int4*)indices, (const float2*)weights, (const int2*)syn,
            rowStart, cursor, edges);
        k_compute<<<N_POST / 8, 512, 0, stream>>>(xTb, edges, rowStart, counts, sw,
                                                  (float2*)d_out, 1 << 30, 0);
    }
}